// Round 1
// baseline (124678.027 us; speedup 1.0000x reference)
//
#include <hip/hip_runtime.h>
#include <math.h>

#define NB    32
#define TIN   512
#define TOUT  512
#define NENC  512
#define NATT  128
#define NFILT 32
#define NU    1024
#define NG    4096
#define NPRE  256
#define NMEL  80
#define KCH   128
#define KS_A  14      // 1792/128
#define KS_D  20      // 2560/128
#define KX_A  768
#define KX_D  1536

// workspace offsets (in floats)
#define WS_AH    0u
#define WS_AC    32768u      // 2 x 32 x 1024 (ping-pong)
#define WS_DH    98304u
#define WS_DC    131072u
#define WS_ACTX  163840u
#define WS_AW    180224u
#define WS_AWCUM 196608u
#define WS_E     212992u
#define WS_PQ    229376u
#define WS_ZA    233472u     // 14 x 32 x 4096
#define WS_ZD    2068480u    // 20 x 32 x 4096
#define WS_PM    4689920u    // 32 x 512 x 128
#define WS_PRE   6787072u    // 512 x 32 x 256
#define WS_ZERO_BYTES (212992u * 4u)

__device__ __forceinline__ float sigm(float x) { return 1.0f / (1.0f + expf(-x)); }

// ---------------- prenet ----------------
// pre[t][b][j] = relu(dec_in[t] @ W1^T);  dec_in[0]=0, dec_in[t]=decoder_inputs[:,:,t-1]
__global__ __launch_bounds__(256) void prenet1_kernel(const float* __restrict__ dec,
                                                      const float* __restrict__ w1,
                                                      float* __restrict__ pre) {
    int t = blockIdx.x;
    __shared__ float xl[NB][NMEL];
    for (int i = threadIdx.x; i < NB * NMEL; i += 256) {
        int b = i / NMEL, m = i % NMEL;
        xl[b][m] = (t == 0) ? 0.0f : dec[(b * NMEL + m) * TOUT + (t - 1)];
    }
    __syncthreads();
    int j = threadIdx.x;
    float acc[NB];
#pragma unroll
    for (int b = 0; b < NB; b++) acc[b] = 0.0f;
    for (int m = 0; m < NMEL; m++) {
        float w = w1[j * NMEL + m];
#pragma unroll
        for (int b = 0; b < NB; b++) acc[b] += xl[b][m] * w;
    }
    for (int b = 0; b < NB; b++) pre[((size_t)t * NB + b) * NPRE + j] = fmaxf(acc[b], 0.0f);
}

// in-place second prenet layer: stage row in LDS, overwrite
__global__ __launch_bounds__(256) void prenet2_kernel(const float* __restrict__ w2,
                                                      float* __restrict__ pre) {
    int t = blockIdx.x;
    __shared__ float hl[NB][NPRE];
    for (int i = threadIdx.x; i < NB * NPRE; i += 256)
        hl[i / NPRE][i % NPRE] = pre[(size_t)t * NB * NPRE + i];
    __syncthreads();
    int j = threadIdx.x;
    float acc[NB];
#pragma unroll
    for (int b = 0; b < NB; b++) acc[b] = 0.0f;
    for (int k = 0; k < NPRE; k++) {
        float w = w2[j * NPRE + k];
#pragma unroll
        for (int b = 0; b < NB; b++) acc[b] += hl[b][k] * w;
    }
    for (int b = 0; b < NB; b++) pre[((size_t)t * NB + b) * NPRE + j] = fmaxf(acc[b], 0.0f);
}

// ---------------- processed_memory ----------------
// pm[b][t][a] = memory[b][t][:] . memory_w[a][:]
__global__ __launch_bounds__(128) void pm_kernel(const float* __restrict__ mem,
                                                 const float* __restrict__ mw,
                                                 float* __restrict__ pm) {
    int b = blockIdx.y, t0 = blockIdx.x * 4;
    __shared__ float ml[4][NENC];
    for (int i = threadIdx.x; i < 4 * NENC; i += 128)
        ml[i / NENC][i % NENC] = mem[((size_t)b * TIN + t0 + i / NENC) * NENC + (i % NENC)];
    __syncthreads();
    int a = threadIdx.x;
    float acc[4] = {0, 0, 0, 0};
    for (int e = 0; e < NENC; e++) {
        float w = mw[a * NENC + e];
#pragma unroll
        for (int tt = 0; tt < 4; tt++) acc[tt] += ml[tt][e] * w;
    }
    for (int tt = 0; tt < 4; tt++)
        pm[((size_t)b * TIN + t0 + tt) * NATT + a] = acc[tt];
}

// ---------------- LSTM GEMV (K-split partials) ----------------
// z[b][col] = xcat[b] . Wrow(col), xcat = [p0 | p1 | h], Wrow = [wih row | whh row]
__global__ __launch_bounds__(256) void lstm_mm_kernel(const float* __restrict__ wih,
                                                      const float* __restrict__ whh,
                                                      int kx,
                                                      const float* __restrict__ p0, int s0, int l0,
                                                      const float* __restrict__ p1, int s1, int l1,
                                                      const float* __restrict__ h,
                                                      float* __restrict__ zpart) {
    int col = blockIdx.x * 256 + threadIdx.x;
    int k0 = blockIdx.y * KCH;
    const float* wb = (k0 < kx) ? (wih + (size_t)col * kx + k0)
                                : (whh + (size_t)col * NU + (k0 - kx));
    const float* xb; int xs;
    if (k0 < l0)           { xb = p0 + k0;             xs = s0; }
    else if (k0 < l0 + l1) { xb = p1 + (k0 - l0);      xs = s1; }
    else                   { xb = h  + (k0 - l0 - l1); xs = NU; }

    float acc[NB];
#pragma unroll
    for (int b = 0; b < NB; b++) acc[b] = 0.0f;
    for (int k4 = 0; k4 < KCH / 4; k4++) {
        float4 w4 = *(const float4*)(wb + k4 * 4);
#pragma unroll
        for (int b = 0; b < NB; b++) {
            float4 x4 = *(const float4*)(xb + (size_t)b * xs + k4 * 4);  // wave-uniform -> scalar loads
            acc[b] += w4.x * x4.x + w4.y * x4.y + w4.z * x4.z + w4.w * x4.w;
        }
    }
    float* zp = zpart + (size_t)blockIdx.y * NB * NG + col;
#pragma unroll
    for (int b = 0; b < NB; b++) zp[(size_t)b * NG] = acc[b];
}

// ---------------- attention-LSTM gates + pq ----------------
__global__ __launch_bounds__(256) void gates_a_pq_kernel(const float* __restrict__ bih,
                                                         const float* __restrict__ bhh,
                                                         const float* __restrict__ qw,
                                                         float* __restrict__ ws, int pp) {
    int b = blockIdx.x;
    __shared__ float ahl[NU];
    float* AH = ws + WS_AH + (size_t)b * NU;
    const float* acO = ws + WS_AC + (size_t)pp * NB * NU + (size_t)b * NU;
    float* acN = ws + WS_AC + (size_t)(1 - pp) * NB * NU + (size_t)b * NU;
    const float* zp = ws + WS_ZA;
    for (int u = threadIdx.x; u < NU; u += 256) {
        float zi = bih[u]          + bhh[u];
        float zf = bih[NU + u]     + bhh[NU + u];
        float zg = bih[2 * NU + u] + bhh[2 * NU + u];
        float zo = bih[3 * NU + u] + bhh[3 * NU + u];
        for (int s = 0; s < KS_A; s++) {
            const float* z = zp + ((size_t)s * NB + b) * NG;
            zi += z[u]; zf += z[NU + u]; zg += z[2 * NU + u]; zo += z[3 * NU + u];
        }
        float c = sigm(zf) * acO[u] + sigm(zi) * tanhf(zg);
        float hv = sigm(zo) * tanhf(c);
        acN[u] = c; AH[u] = hv; ahl[u] = hv;
    }
    __syncthreads();
    if (threadIdx.x < NATT) {
        int a = threadIdx.x;
        float s = 0.0f;
        const float* qr = qw + (size_t)a * NU;
        for (int k = 0; k < NU; k++) s += ahl[k] * qr[k];
        ws[WS_PQ + b * NATT + a] = s;
    }
}

// ---------------- energies: conv + dense + tanh + v-dot + mask ----------------
__global__ __launch_bounds__(128) void energies_kernel(const float* __restrict__ pm,
                                                       const float* __restrict__ wc,
                                                       const float* __restrict__ ldw,
                                                       const float* __restrict__ vw,
                                                       const int* __restrict__ mlen,
                                                       const float* __restrict__ ws_aw,
                                                       const float* __restrict__ ws_awcum,
                                                       const float* __restrict__ ws_pq,
                                                       float* __restrict__ ws_e) {
    int b = blockIdx.y, tc = blockIdx.x;
    int tt = threadIdx.x & 31, sub = threadIdx.x >> 5;
    int t = tc * 32 + tt;
    __shared__ float awl[TIN], cuml[TIN], locl[32][33], pql[NATT], ep[32][4];
    for (int i = threadIdx.x; i < TIN; i += 128) {
        awl[i]  = ws_aw[b * TIN + i];
        cuml[i] = ws_awcum[b * TIN + i];
    }
    for (int i = threadIdx.x; i < NATT; i += 128) pql[i] = ws_pq[b * NATT + i];
    __syncthreads();
    for (int f = sub * 8; f < sub * 8 + 8; f++) {
        float s = 0.0f;
        const float* wA = wc + f * 62;
        const float* wB = wA + 31;
        for (int d = 0; d < 31; d++) {
            int tp = t + d - 15;
            if (tp >= 0 && tp < TIN) s += awl[tp] * wA[d] + cuml[tp] * wB[d];
        }
        locl[tt][f] = s;
    }
    __syncthreads();
    float acc = 0.0f;
    const float* pmb = pm + ((size_t)b * TIN + t) * NATT;
    for (int a = sub * 32; a < sub * 32 + 32; a++) {
        float s = pql[a] + pmb[a];
        const float* lw = ldw + a * 32;
#pragma unroll
        for (int f = 0; f < 32; f++) s += locl[tt][f] * lw[f];
        acc += tanhf(s) * vw[a];
    }
    ep[tt][sub] = acc;
    __syncthreads();
    if (sub == 0) {
        float ev = ep[tt][0] + ep[tt][1] + ep[tt][2] + ep[tt][3];
        if (t >= mlen[b]) ev = -3.0e38f;
        ws_e[b * TIN + t] = ev;
    }
}

// ---------------- softmax + context (+aw/awcum/alignments) ----------------
__global__ __launch_bounds__(256) void softmax_ctx_kernel(const float* __restrict__ mem,
                                                          float* __restrict__ ws,
                                                          float* __restrict__ out_align, int step) {
    int b = blockIdx.y, ec = blockIdx.x;
    __shared__ float el[TIN];
    __shared__ float red[256];
    __shared__ float part[4][64];
    const float* E = ws + WS_E + b * TIN;
    for (int i = threadIdx.x; i < TIN; i += 256) el[i] = E[i];
    __syncthreads();
    red[threadIdx.x] = fmaxf(el[threadIdx.x], el[threadIdx.x + 256]);
    __syncthreads();
    for (int s = 128; s > 0; s >>= 1) {
        if (threadIdx.x < s) red[threadIdx.x] = fmaxf(red[threadIdx.x], red[threadIdx.x + s]);
        __syncthreads();
    }
    float mx = red[0];
    __syncthreads();
    float p0 = expf(el[threadIdx.x] - mx), p1 = expf(el[threadIdx.x + 256] - mx);
    el[threadIdx.x] = p0; el[threadIdx.x + 256] = p1;
    red[threadIdx.x] = p0 + p1;
    __syncthreads();
    for (int s = 128; s > 0; s >>= 1) {
        if (threadIdx.x < s) red[threadIdx.x] += red[threadIdx.x + s];
        __syncthreads();
    }
    float inv = 1.0f / red[0];
    int ei = ec * 64 + (threadIdx.x & 63), tp4 = threadIdx.x >> 6;
    float acc = 0.0f;
    const float* mb = mem + (size_t)b * TIN * NENC + ei;
    for (int t = tp4 * 128; t < tp4 * 128 + 128; t++) acc += el[t] * mb[(size_t)t * NENC];
    part[tp4][threadIdx.x & 63] = acc;
    __syncthreads();
    if (threadIdx.x < 64) {
        float ctx = (part[0][threadIdx.x] + part[1][threadIdx.x] +
                     part[2][threadIdx.x] + part[3][threadIdx.x]) * inv;
        ws[WS_ACTX + b * NENC + ec * 64 + threadIdx.x] = ctx;
    }
    if (ec == 0) {
        for (int i = threadIdx.x; i < TIN; i += 256) {
            float a_ = el[i] * inv;
            ws[WS_AW + b * TIN + i] = a_;
            ws[WS_AWCUM + b * TIN + i] += a_;
            out_align[((size_t)b * TOUT + step) * TIN + i] = a_;
        }
    }
}

// ---------------- decoder-LSTM gates + projection ----------------
__global__ __launch_bounds__(256) void proj_gates_d_kernel(const float* __restrict__ bih,
                                                           const float* __restrict__ bhh,
                                                           const float* __restrict__ pw,
                                                           const float* __restrict__ pb,
                                                           const float* __restrict__ gw,
                                                           const float* __restrict__ gb,
                                                           float* __restrict__ ws,
                                                           float* __restrict__ out, int step) {
    int b = blockIdx.x;
    __shared__ float dhc[NU + NENC];
    const float* zp = ws + WS_ZD;
    float* DH = ws + WS_DH + (size_t)b * NU;
    float* DC = ws + WS_DC + (size_t)b * NU;
    for (int u = threadIdx.x; u < NU; u += 256) {
        float zi = bih[u]          + bhh[u];
        float zf = bih[NU + u]     + bhh[NU + u];
        float zg = bih[2 * NU + u] + bhh[2 * NU + u];
        float zo = bih[3 * NU + u] + bhh[3 * NU + u];
        for (int s = 0; s < KS_D; s++) {
            const float* z = zp + ((size_t)s * NB + b) * NG;
            zi += z[u]; zf += z[NU + u]; zg += z[2 * NU + u]; zo += z[3 * NU + u];
        }
        float c = sigm(zf) * DC[u] + sigm(zi) * tanhf(zg);
        float hv = sigm(zo) * tanhf(c);
        DC[u] = c; DH[u] = hv; dhc[u] = hv;
    }
    for (int i = threadIdx.x; i < NENC; i += 256) dhc[NU + i] = ws[WS_ACTX + b * NENC + i];
    __syncthreads();
    if (threadIdx.x < NMEL + 1) {
        int col = threadIdx.x;
        const float* wr = (col < NMEL) ? (pw + (size_t)col * (NU + NENC)) : gw;
        float s = (col < NMEL) ? pb[col] : gb[0];
        for (int k = 0; k < NU + NENC; k++) s += dhc[k] * wr[k];
        if (col < NMEL) out[((size_t)b * NMEL + col) * TOUT + step] = s;
        else            out[(size_t)NB * NMEL * TOUT + (size_t)b * TOUT + step] = s;
    }
}

extern "C" void kernel_launch(void* const* d_in, const int* in_sizes, int n_in,
                              void* d_out, int out_size, void* d_ws, size_t ws_size,
                              hipStream_t stream) {
    const float* memory = (const float*)d_in[0];
    const float* dec    = (const float*)d_in[1];
    const int*   mlen   = (const int*)d_in[2];
    const float* pw1    = (const float*)d_in[3];
    const float* pw2    = (const float*)d_in[4];
    const float* awih   = (const float*)d_in[5];
    const float* awhh   = (const float*)d_in[6];
    const float* abih   = (const float*)d_in[7];
    const float* abhh   = (const float*)d_in[8];
    const float* qw     = (const float*)d_in[9];
    const float* mw     = (const float*)d_in[10];
    const float* vw     = (const float*)d_in[11];
    const float* wc     = (const float*)d_in[12];
    const float* ldw    = (const float*)d_in[13];
    const float* dwih   = (const float*)d_in[14];
    const float* dwhh   = (const float*)d_in[15];
    const float* dbih   = (const float*)d_in[16];
    const float* dbhh   = (const float*)d_in[17];
    const float* pjw    = (const float*)d_in[18];
    const float* pjb    = (const float*)d_in[19];
    const float* gtw    = (const float*)d_in[20];
    const float* gtb    = (const float*)d_in[21];
    float* ws  = (float*)d_ws;
    float* out = (float*)d_out;
    float* out_align = out + (size_t)NB * NMEL * TOUT + (size_t)NB * TOUT;

    hipMemsetAsync(d_ws, 0, WS_ZERO_BYTES, stream);
    prenet1_kernel<<<TOUT, 256, 0, stream>>>(dec, pw1, ws + WS_PRE);
    prenet2_kernel<<<TOUT, 256, 0, stream>>>(pw2, ws + WS_PRE);
    pm_kernel<<<dim3(TIN / 4, NB), 128, 0, stream>>>(memory, mw, ws + WS_PM);

    for (int t = 0; t < TOUT; ++t) {
        int pp = t & 1;
        lstm_mm_kernel<<<dim3(16, KS_A), 256, 0, stream>>>(
            awih, awhh, KX_A,
            ws + WS_PRE + (size_t)t * NB * NPRE, NPRE, NPRE,
            ws + WS_ACTX, NENC, NENC,
            ws + WS_AH,
            ws + WS_ZA);
        gates_a_pq_kernel<<<NB, 256, 0, stream>>>(abih, abhh, qw, ws, pp);
        energies_kernel<<<dim3(16, NB), 128, 0, stream>>>(
            ws + WS_PM, wc, ldw, vw, mlen,
            ws + WS_AW, ws + WS_AWCUM, ws + WS_PQ, ws + WS_E);
        softmax_ctx_kernel<<<dim3(8, NB), 256, 0, stream>>>(memory, ws, out_align, t);
        lstm_mm_kernel<<<dim3(16, KS_D), 256, 0, stream>>>(
            dwih, dwhh, KX_D,
            ws + WS_AH, NU, NU,
            ws + WS_ACTX, NENC, NENC,
            ws + WS_DH,
            ws + WS_ZD);
        proj_gates_d_kernel<<<NB, 256, 0, stream>>>(dbih, dbhh, pjw, pjb, gtw, gtb, ws, out, t);
    }
}